// Round 1
// baseline (1004.755 us; speedup 1.0000x reference)
//
#include <hip/hip_runtime.h>

// GRU (B=4096, T=2048, H=8, I=4) + fused FC (O=4), fp32.
// Decomposition: 8 lanes per batch element; lane i owns hidden elem i.
// Each lane computes its 3 gate rows, its own sigmoid/tanh, then an 8-wide
// shuffle gather rebuilds the replicated h vector for next-step dots + FC.
// 4096*8 = 32768 threads = 512 waves; block=64 so 512 WGs spread over 256 CUs.

#define GRU_T 2048
#define GRU_H 8
#define GRU_I 4
#define GRU_O 4

__device__ __forceinline__ float sigmoid_fast(float v) {
    return 1.0f / (1.0f + __expf(-v));
}
__device__ __forceinline__ float tanh_fast(float v) {
    // tanh(v) = 1 - 2/(1+exp(2v));  exp(2v)->0 => -1, exp->inf => +1 (safe)
    return 1.0f - 2.0f / (1.0f + __expf(2.0f * v));
}

__global__ __launch_bounds__(64) void gru_fc_kernel(
    const float* __restrict__ x,
    const float* __restrict__ W_ih,
    const float* __restrict__ W_hh,
    const float* __restrict__ b_ih,
    const float* __restrict__ b_hh,
    const float* __restrict__ W_fc,
    const float* __restrict__ b_fc,
    float* __restrict__ out)
{
    constexpr int T = GRU_T, H = GRU_H, I = GRU_I, O = GRU_O;

    const int tid   = blockIdx.x * 64 + threadIdx.x;
    const int b     = tid >> 3;          // batch element
    const int i     = tid & 7;           // hidden index this lane owns
    const int lane  = threadIdx.x;       // block==wave==64
    const int gbase = lane & 56;         // first lane of this 8-lane group

    // ---- weights into registers (loaded once; tiny arrays, unrolled) ----
    float wi_r[I], wi_z[I], wi_n[I];
#pragma unroll
    for (int k = 0; k < I; ++k) {
        wi_r[k] = W_ih[(0 * H + i) * I + k];
        wi_z[k] = W_ih[(1 * H + i) * I + k];
        wi_n[k] = W_ih[(2 * H + i) * I + k];
    }
    float wh_r[H], wh_z[H], wh_n[H];
#pragma unroll
    for (int k = 0; k < H; ++k) {
        wh_r[k] = W_hh[(0 * H + i) * H + k];
        wh_z[k] = W_hh[(1 * H + i) * H + k];
        wh_n[k] = W_hh[(2 * H + i) * H + k];
    }
    const float br  = b_ih[i]         + b_hh[i];          // r,z biases combine
    const float bz  = b_ih[H + i]     + b_hh[H + i];
    const float bxn = b_ih[2 * H + i];                    // n biases stay split
    const float bhn = b_hh[2 * H + i];

    const int o = i & 3;                 // FC output index (lanes 4-7 duplicate 0-3)
    float wf[H];
#pragma unroll
    for (int k = 0; k < H; ++k) wf[k] = W_fc[o * H + k];
    const float bo = b_fc[o];

    // ---- state ----
    float h[H];
#pragma unroll
    for (int k = 0; k < H; ++k) h[k] = 0.0f;
    float hown = 0.0f;                   // this lane's own h element (avoids h[i] dyn-index)

    const float4* __restrict__ xp = reinterpret_cast<const float4*>(x) + (size_t)b * T;
    float* __restrict__ op = out + (size_t)b * T * O + o;
    const bool writer = (i < 4);

    float4 xt = xp[0];                   // software-pipelined x prefetch
    for (int t = 0; t < T; ++t) {
        const float4 xc = xt;
        if (t + 1 < T) xt = xp[t + 1];

        // gate pre-activations: 6 independent FMA chains (good single-wave ILP)
        float ar = br, az = bz, axn = bxn, ahn = bhn;
        ar  = fmaf(wi_r[0], xc.x, ar);  ar  = fmaf(wi_r[1], xc.y, ar);
        ar  = fmaf(wi_r[2], xc.z, ar);  ar  = fmaf(wi_r[3], xc.w, ar);
        az  = fmaf(wi_z[0], xc.x, az);  az  = fmaf(wi_z[1], xc.y, az);
        az  = fmaf(wi_z[2], xc.z, az);  az  = fmaf(wi_z[3], xc.w, az);
        axn = fmaf(wi_n[0], xc.x, axn); axn = fmaf(wi_n[1], xc.y, axn);
        axn = fmaf(wi_n[2], xc.z, axn); axn = fmaf(wi_n[3], xc.w, axn);
#pragma unroll
        for (int k = 0; k < H; ++k) {
            ar  = fmaf(wh_r[k], h[k], ar);
            az  = fmaf(wh_z[k], h[k], az);
            ahn = fmaf(wh_n[k], h[k], ahn);
        }

        const float r  = sigmoid_fast(ar);
        const float z  = sigmoid_fast(az);
        const float n  = tanh_fast(fmaf(r, ahn, axn));
        const float hn = fmaf(z, hown - n, n);   // (1-z)*n + z*h
        hown = hn;

        // gather the group's 8 new h elements into every lane
#pragma unroll
        for (int k = 0; k < H; ++k) h[k] = __shfl(hn, gbase + k, 64);

        // fused FC on the fresh h
        float acc = bo;
#pragma unroll
        for (int k = 0; k < H; ++k) acc = fmaf(wf[k], h[k], acc);
        if (writer) op[(size_t)t * O] = acc;
    }
}

extern "C" void kernel_launch(void* const* d_in, const int* in_sizes, int n_in,
                              void* d_out, int out_size, void* d_ws, size_t ws_size,
                              hipStream_t stream) {
    const float* x    = (const float*)d_in[0];
    const float* W_ih = (const float*)d_in[1];
    const float* W_hh = (const float*)d_in[2];
    const float* b_ih = (const float*)d_in[3];
    const float* b_hh = (const float*)d_in[4];
    const float* W_fc = (const float*)d_in[5];
    const float* b_fc = (const float*)d_in[6];
    float* out = (float*)d_out;

    const int B = in_sizes[0] / (GRU_T * GRU_I);   // 4096
    dim3 grid((unsigned)(B * GRU_H / 64)), block(64);
    hipLaunchKernelGGL(gru_fc_kernel, grid, block, 0, stream,
                       x, W_ih, W_hh, b_ih, b_hh, W_fc, b_fc, out);
}

// Round 2
// 621.563 us; speedup vs baseline: 1.6165x; 1.6165x over previous
//
#include <hip/hip_runtime.h>

// GRU (B=4096, T=2048, H=8, I=4) + fused FC (O=4), fp32.
// 8 lanes per batch element; lane i owns hidden elem i. 512 waves total
// (structural cap = B*H lanes), so ~1 wave per busy SIMD: all memory latency
// must be hidden in-wave -> 8-deep double-buffered register prefetch of x.
// Transcendentals via raw v_exp_f32 / v_rcp_f32 (threshold is 1.9e-2).

#define GRU_T 2048
#define GRU_H 8
#define GRU_I 4
#define GRU_O 4
#define PFD   8        // prefetch depth (timesteps); T % PFD == 0

__device__ __forceinline__ float fast_rcp(float x)  { return __builtin_amdgcn_rcpf(x); }
__device__ __forceinline__ float fast_exp2(float x) { return __builtin_amdgcn_exp2f(x); }

// sigmoid(v) = 1/(1+exp(-v)) = rcp(1 + exp2(-v*log2e))
__device__ __forceinline__ float sigmoid_fast(float v) {
    return fast_rcp(1.0f + fast_exp2(-1.4426950408889634f * v));
}
// tanh(v) = 1 - 2/(1+exp(2v)) = 1 - 2*rcp(1 + exp2(v*2*log2e))
__device__ __forceinline__ float tanh_fast(float v) {
    return 1.0f - 2.0f * fast_rcp(1.0f + fast_exp2(2.8853900817779268f * v));
}

__global__ __launch_bounds__(64, 1) void gru_fc_kernel(
    const float* __restrict__ x,
    const float* __restrict__ W_ih,
    const float* __restrict__ W_hh,
    const float* __restrict__ b_ih,
    const float* __restrict__ b_hh,
    const float* __restrict__ W_fc,
    const float* __restrict__ b_fc,
    float* __restrict__ out)
{
    constexpr int T = GRU_T, H = GRU_H, I = GRU_I, O = GRU_O;

    const int tid   = blockIdx.x * 64 + threadIdx.x;
    const int b     = tid >> 3;          // batch element
    const int i     = tid & 7;           // hidden index this lane owns
    const int lane  = threadIdx.x;
    const int gbase = lane & 56;         // first lane of this 8-lane group

    // ---- weights into registers ----
    float wi_r[I], wi_z[I], wi_n[I];
#pragma unroll
    for (int k = 0; k < I; ++k) {
        wi_r[k] = W_ih[(0 * H + i) * I + k];
        wi_z[k] = W_ih[(1 * H + i) * I + k];
        wi_n[k] = W_ih[(2 * H + i) * I + k];
    }
    float wh_r[H], wh_z[H], wh_n[H];
#pragma unroll
    for (int k = 0; k < H; ++k) {
        wh_r[k] = W_hh[(0 * H + i) * H + k];
        wh_z[k] = W_hh[(1 * H + i) * H + k];
        wh_n[k] = W_hh[(2 * H + i) * H + k];
    }
    const float br  = b_ih[i]         + b_hh[i];
    const float bz  = b_ih[H + i]     + b_hh[H + i];
    const float bxn = b_ih[2 * H + i];
    const float bhn = b_hh[2 * H + i];

    const int o = i & 3;                 // FC output index (lanes 4-7 duplicate)
    float wf[H];
#pragma unroll
    for (int k = 0; k < H; ++k) wf[k] = W_fc[o * H + k];
    const float bo = b_fc[o];

    // pre-hoisted ds_bpermute byte addresses for the 8-wide h gather
    int perm_addr[H];
#pragma unroll
    for (int k = 0; k < H; ++k) perm_addr[k] = (gbase + k) << 2;

    // ---- state ----
    float h[H];
#pragma unroll
    for (int k = 0; k < H; ++k) h[k] = 0.0f;
    float hown = 0.0f;

    const float4* __restrict__ xp = reinterpret_cast<const float4*>(x) + (size_t)b * T;
    float* __restrict__ op = out + (size_t)b * T * O + o;
    const bool writer = (i < 4);

    // ---- 8-deep double-buffered register prefetch of x ----
    float4 buf[PFD];
#pragma unroll
    for (int j = 0; j < PFD; ++j) buf[j] = xp[j];

    for (int tb = 0; tb < T; tb += PFD) {
        // issue next block's loads NOW; wrap at end (T pow2) - values unused
        const int tnext = (tb + PFD) & (T - 1);
        float4 nxt[PFD];
#pragma unroll
        for (int j = 0; j < PFD; ++j) nxt[j] = xp[tnext + j];

#pragma unroll
        for (int j = 0; j < PFD; ++j) {
            const float4 xc = buf[j];

            float ar = br, az = bz, axn = bxn, ahn = bhn;
            ar  = fmaf(wi_r[0], xc.x, ar);  ar  = fmaf(wi_r[1], xc.y, ar);
            ar  = fmaf(wi_r[2], xc.z, ar);  ar  = fmaf(wi_r[3], xc.w, ar);
            az  = fmaf(wi_z[0], xc.x, az);  az  = fmaf(wi_z[1], xc.y, az);
            az  = fmaf(wi_z[2], xc.z, az);  az  = fmaf(wi_z[3], xc.w, az);
            axn = fmaf(wi_n[0], xc.x, axn); axn = fmaf(wi_n[1], xc.y, axn);
            axn = fmaf(wi_n[2], xc.z, axn); axn = fmaf(wi_n[3], xc.w, axn);
#pragma unroll
            for (int k = 0; k < H; ++k) {
                ar  = fmaf(wh_r[k], h[k], ar);
                az  = fmaf(wh_z[k], h[k], az);
                ahn = fmaf(wh_n[k], h[k], ahn);
            }

            const float r  = sigmoid_fast(ar);
            const float z  = sigmoid_fast(az);
            const float n  = tanh_fast(fmaf(r, ahn, axn));
            const float hn = fmaf(z, hown - n, n);   // (1-z)*n + z*h
            hown = hn;

            // gather the group's 8 new h elements into every lane
            const int hn_i = __float_as_int(hn);
#pragma unroll
            for (int k = 0; k < H; ++k)
                h[k] = __int_as_float(__builtin_amdgcn_ds_bpermute(perm_addr[k], hn_i));

            // fused FC on the fresh h
            float acc = bo;
#pragma unroll
            for (int k = 0; k < H; ++k) acc = fmaf(wf[k], h[k], acc);
            if (writer) op[(size_t)(tb + j) * O] = acc;
        }

#pragma unroll
        for (int j = 0; j < PFD; ++j) buf[j] = nxt[j];
    }
}

extern "C" void kernel_launch(void* const* d_in, const int* in_sizes, int n_in,
                              void* d_out, int out_size, void* d_ws, size_t ws_size,
                              hipStream_t stream) {
    const float* x    = (const float*)d_in[0];
    const float* W_ih = (const float*)d_in[1];
    const float* W_hh = (const float*)d_in[2];
    const float* b_ih = (const float*)d_in[3];
    const float* b_hh = (const float*)d_in[4];
    const float* W_fc = (const float*)d_in[5];
    const float* b_fc = (const float*)d_in[6];
    float* out = (float*)d_out;

    const int B = in_sizes[0] / (GRU_T * GRU_I);   // 4096
    dim3 grid((unsigned)(B * GRU_H / 64)), block(64);
    hipLaunchKernelGGL(gru_fc_kernel, grid, block, 0, stream,
                       x, W_ih, W_hh, b_ih, b_hh, W_fc, b_fc, out);
}

// Round 3
// 533.737 us; speedup vs baseline: 1.8825x; 1.1645x over previous
//
#include <hip/hip_runtime.h>

// GRU (B=4096, T=2048, H=8, I=4) + fused FC (O=4), fp32.
// 8 lanes per batch element; lane i owns hidden elem i. 512 waves total.
// R2: h all-gather via DPP butterfly (VALU pipe, ~2cyc/op) instead of
// ds_bpermute (LDS crossbar, ~120cyc on the recurrence critical path).
// Gathered order per lane is h[i ^ mu[j]], mu=[0,1,2,3,7,6,5,4]; weights are
// loaded pre-permuted by mu so dot products are oblivious to the order.

#define GRU_T 2048
#define GRU_H 8
#define GRU_I 4
#define GRU_O 4
#define PFD   8        // x prefetch depth (timesteps); T % PFD == 0

#define DPP_XOR1 0xB1   // quad_perm [1,0,3,2]
#define DPP_XOR2 0x4E   // quad_perm [2,3,0,1]
#define DPP_XOR7 0x141  // row_half_mirror (xor7 within aligned 8-lane halves)

template <int CTRL>
__device__ __forceinline__ float dpp_movf(float v) {
    return __int_as_float(
        __builtin_amdgcn_mov_dpp(__float_as_int(v), CTRL, 0xf, 0xf, true));
}

__device__ __forceinline__ float fast_rcp(float x)  { return __builtin_amdgcn_rcpf(x); }
__device__ __forceinline__ float fast_exp2(float x) { return __builtin_amdgcn_exp2f(x); }

__device__ __forceinline__ float sigmoid_fast(float v) {
    return fast_rcp(1.0f + fast_exp2(-1.4426950408889634f * v));
}
__device__ __forceinline__ float tanh_fast(float v) {
    return 1.0f - 2.0f * fast_rcp(1.0f + fast_exp2(2.8853900817779268f * v));
}

__global__ __launch_bounds__(64, 1) void gru_fc_kernel(
    const float* __restrict__ x,
    const float* __restrict__ W_ih,
    const float* __restrict__ W_hh,
    const float* __restrict__ b_ih,
    const float* __restrict__ b_hh,
    const float* __restrict__ W_fc,
    const float* __restrict__ b_fc,
    float* __restrict__ out)
{
    constexpr int T = GRU_T, H = GRU_H, I = GRU_I, O = GRU_O;

    const int tid = blockIdx.x * 64 + threadIdx.x;
    const int b   = tid >> 3;            // batch element
    const int i   = tid & 7;             // hidden index this lane owns

    // gather-order permutation: slot j holds h[i ^ mu[j]]
    const int mu[H] = {0, 1, 2, 3, 7, 6, 5, 4};

    // ---- weights into registers (W_hh / W_fc columns permuted by mu) ----
    float wi_r[I], wi_z[I], wi_n[I];
#pragma unroll
    for (int k = 0; k < I; ++k) {
        wi_r[k] = W_ih[(0 * H + i) * I + k];
        wi_z[k] = W_ih[(1 * H + i) * I + k];
        wi_n[k] = W_ih[(2 * H + i) * I + k];
    }
    float wh_r[H], wh_z[H], wh_n[H];
#pragma unroll
    for (int j = 0; j < H; ++j) {
        const int k = i ^ mu[j];
        wh_r[j] = W_hh[(0 * H + i) * H + k];
        wh_z[j] = W_hh[(1 * H + i) * H + k];
        wh_n[j] = W_hh[(2 * H + i) * H + k];
    }
    const float br  = b_ih[i]         + b_hh[i];
    const float bz  = b_ih[H + i]     + b_hh[H + i];
    const float bxn = b_ih[2 * H + i];
    const float bhn = b_hh[2 * H + i];

    const int o = i & 3;                 // FC output index (lanes 4-7 duplicate)
    float wf[H];
#pragma unroll
    for (int j = 0; j < H; ++j) wf[j] = W_fc[o * H + (i ^ mu[j])];
    const float bo = b_fc[o];

    // ---- state: h in mu-permuted order ----
    float h[H];
#pragma unroll
    for (int j = 0; j < H; ++j) h[j] = 0.0f;
    float hown = 0.0f;

    const float4* __restrict__ xp = reinterpret_cast<const float4*>(x) + (size_t)b * T;
    float* __restrict__ op = out + (size_t)b * T * O;   // all 8 lanes store

    // ---- PFD-deep double-buffered register prefetch of x ----
    float4 buf[PFD];
#pragma unroll
    for (int j = 0; j < PFD; ++j) buf[j] = xp[j];

    float accA = 0.0f;                   // even-step FC result

    for (int tb = 0; tb < T; tb += PFD) {
        const int tnext = (tb + PFD) & (T - 1);   // wrap at end (values unused)
        float4 nxt[PFD];
#pragma unroll
        for (int j = 0; j < PFD; ++j) nxt[j] = xp[tnext + j];

#pragma unroll
        for (int j = 0; j < PFD; ++j) {
            const float4 xc = buf[j];

            float ar = br, az = bz, axn = bxn, ahn = bhn;
            ar  = fmaf(wi_r[0], xc.x, ar);  ar  = fmaf(wi_r[1], xc.y, ar);
            ar  = fmaf(wi_r[2], xc.z, ar);  ar  = fmaf(wi_r[3], xc.w, ar);
            az  = fmaf(wi_z[0], xc.x, az);  az  = fmaf(wi_z[1], xc.y, az);
            az  = fmaf(wi_z[2], xc.z, az);  az  = fmaf(wi_z[3], xc.w, az);
            axn = fmaf(wi_n[0], xc.x, axn); axn = fmaf(wi_n[1], xc.y, axn);
            axn = fmaf(wi_n[2], xc.z, axn); axn = fmaf(wi_n[3], xc.w, axn);
#pragma unroll
            for (int k = 0; k < H; ++k) {
                ar  = fmaf(wh_r[k], h[k], ar);
                az  = fmaf(wh_z[k], h[k], az);
                ahn = fmaf(wh_n[k], h[k], ahn);
            }

            const float r  = sigmoid_fast(ar);
            const float z  = sigmoid_fast(az);
            const float n  = tanh_fast(fmaf(r, ahn, axn));
            const float hn = fmaf(z, hown - n, n);   // (1-z)*n + z*h
            hown = hn;

            // DPP butterfly all-gather: h[j] = hn of lane (i ^ mu[j])
            h[0] = hn;
            h[1] = dpp_movf<DPP_XOR1>(hn);
            h[2] = dpp_movf<DPP_XOR2>(hn);
            h[3] = dpp_movf<DPP_XOR2>(h[1]);
            h[4] = dpp_movf<DPP_XOR7>(hn);
            h[5] = dpp_movf<DPP_XOR7>(h[1]);
            h[6] = dpp_movf<DPP_XOR7>(h[2]);
            h[7] = dpp_movf<DPP_XOR7>(h[3]);

            // fused FC on the fresh h (all lanes; lanes 4-7 duplicate 0-3)
            float acc = bo;
#pragma unroll
            for (int k = 0; k < H; ++k) acc = fmaf(wf[k], h[k], acc);

            // even/odd pair store: one coalesced 8-dword store per group / 2 steps
            if ((j & 1) == 0) {
                accA = acc;
            } else {
                const float val = (i < 4) ? accA : acc;
                op[(size_t)((tb + j) >> 1) * 8 + i] = val;
            }
        }

#pragma unroll
        for (int j = 0; j < PFD; ++j) buf[j] = nxt[j];
    }
}

extern "C" void kernel_launch(void* const* d_in, const int* in_sizes, int n_in,
                              void* d_out, int out_size, void* d_ws, size_t ws_size,
                              hipStream_t stream) {
    const float* x    = (const float*)d_in[0];
    const float* W_ih = (const float*)d_in[1];
    const float* W_hh = (const float*)d_in[2];
    const float* b_ih = (const float*)d_in[3];
    const float* b_hh = (const float*)d_in[4];
    const float* W_fc = (const float*)d_in[5];
    const float* b_fc = (const float*)d_in[6];
    float* out = (float*)d_out;

    const int B = in_sizes[0] / (GRU_T * GRU_I);   // 4096
    dim3 grid((unsigned)(B * GRU_H / 64)), block(64);
    hipLaunchKernelGGL(gru_fc_kernel, grid, block, 0, stream,
                       x, W_ih, W_hh, b_ih, b_hh, W_fc, b_fc, out);
}